// Round 1
// baseline (310.982 us; speedup 1.0000x reference)
//
#include <hip/hip_runtime.h>

// 2-layer LSTM, B=4096, S=512, F=8, H=10 + FC(10->1) on last step.
// Layout: 16 lanes per batch element (lane = hidden unit, 10 active),
// 4 elements per wave, 256 blocks x 256 threads = 1024 waves = 1/SIMD.
// Weights fully register-resident (152 VGPR/lane); h broadcast via __shfl
// within the 16-lane group; x prefetched 3 steps ahead from HBM.

#define L2E 1.4426950408889634f

__device__ __forceinline__ float sigm(float z) {
    // 1/(1+e^-z) = rcp(1 + 2^(-z*log2e))
    return __builtin_amdgcn_rcpf(1.0f + __builtin_amdgcn_exp2f(-L2E * z));
}
__device__ __forceinline__ float tanh_(float z) {
    // tanh(z) = 1 - 2/(1+e^{2z})
    return 1.0f - 2.0f * __builtin_amdgcn_rcpf(1.0f + __builtin_amdgcn_exp2f((2.0f * L2E) * z));
}

__global__ __launch_bounds__(256, 1)
void lstm2_kernel(const float* __restrict__ x,
                  const float* __restrict__ hid,
                  const float* __restrict__ cel,
                  const float* __restrict__ Wih0, const float* __restrict__ Whh0,
                  const float* __restrict__ bih0, const float* __restrict__ bhh0,
                  const float* __restrict__ Wih1, const float* __restrict__ Whh1,
                  const float* __restrict__ bih1, const float* __restrict__ bhh1,
                  const float* __restrict__ Wfc,  const float* __restrict__ bfc,
                  float* __restrict__ out)
{
    const int tid = threadIdx.x;
    const int l16 = tid & 15;          // lane within group
    const int grp = tid >> 4;          // group within block (16 groups)
    const int e   = blockIdx.x * 16 + grp;   // batch element, 0..4095
    const int j   = (l16 < 10) ? l16 : 0;    // hidden unit owned by this lane
    const bool act = (l16 < 10);

    // ---- loop-invariant weights into registers (rows j, 10+j, 20+j, 30+j) ----
    float wih0[4][8], whh0[4][10], wih1[4][10], whh1[4][10], b0[4], b1[4];
    #pragma unroll
    for (int g = 0; g < 4; ++g) {
        const int r = g * 10 + j;
        #pragma unroll
        for (int k = 0; k < 8; ++k)  wih0[g][k] = Wih0[r * 8 + k];
        #pragma unroll
        for (int k = 0; k < 10; ++k) whh0[g][k] = Whh0[r * 10 + k];
        #pragma unroll
        for (int k = 0; k < 10; ++k) wih1[g][k] = Wih1[r * 10 + k];
        #pragma unroll
        for (int k = 0; k < 10; ++k) whh1[g][k] = Whh1[r * 10 + k];
        b0[g] = bih0[r] + bhh0[r];
        b1[g] = bih1[r] + bhh1[r];
    }
    const float wfc = act ? Wfc[j] : 0.0f;

    // ---- initial state ----
    float h0v[10], h1v[10];
    #pragma unroll
    for (int k = 0; k < 10; ++k) h0v[k] = hid[e * 10 + k];
    #pragma unroll
    for (int k = 0; k < 10; ++k) h1v[k] = hid[40960 + e * 10 + k];
    float c0 = cel[e * 10 + j];
    float c1 = cel[40960 + e * 10 + j];
    float h0j = h0v[j], h1j = h1v[j];

    const float4* __restrict__ xp = reinterpret_cast<const float4*>(x + (size_t)e * 4096);

    // 4-deep register prefetch of x (2 float4 = one step's 8 inputs)
    float4 xb0[2], xb1[2], xb2[2], xb3[2];
    xb0[0] = xp[0]; xb0[1] = xp[1];
    xb1[0] = xp[2]; xb1[1] = xp[3];
    xb2[0] = xp[4]; xb2[1] = xp[5];
    xb3[0] = xp[6]; xb3[1] = xp[7];

#define STEP(XB, TNEXT)                                                         \
    {                                                                           \
        float xv[8];                                                            \
        xv[0] = XB[0].x; xv[1] = XB[0].y; xv[2] = XB[0].z; xv[3] = XB[0].w;     \
        xv[4] = XB[1].x; xv[5] = XB[1].y; xv[6] = XB[1].z; xv[7] = XB[1].w;     \
        int tn = (TNEXT) > 511 ? 511 : (TNEXT);                                 \
        XB[0] = xp[2 * tn]; XB[1] = xp[2 * tn + 1];                             \
        float a[4];                                                             \
        _Pragma("unroll")                                                       \
        for (int g = 0; g < 4; ++g) {                                           \
            float s = b0[g];                                                    \
            _Pragma("unroll")                                                   \
            for (int k = 0; k < 8; ++k) s = fmaf(wih0[g][k], xv[k], s);         \
            a[g] = s;                                                           \
        }                                                                       \
        _Pragma("unroll")                                                       \
        for (int g = 0; g < 4; ++g) {                                           \
            float s = a[g];                                                     \
            _Pragma("unroll")                                                   \
            for (int k = 0; k < 10; ++k) s = fmaf(whh0[g][k], h0v[k], s);       \
            a[g] = s;                                                           \
        }                                                                       \
        float i0 = sigm(a[0]), f0 = sigm(a[1]);                                 \
        float g0 = tanh_(a[2]), o0 = sigm(a[3]);                                \
        c0 = fmaf(f0, c0, i0 * g0);                                             \
        h0j = o0 * tanh_(c0);                                                   \
        _Pragma("unroll")                                                       \
        for (int k = 0; k < 10; ++k) h0v[k] = __shfl(h0j, k, 16);               \
        _Pragma("unroll")                                                       \
        for (int g = 0; g < 4; ++g) {                                           \
            float s = b1[g];                                                    \
            _Pragma("unroll")                                                   \
            for (int k = 0; k < 10; ++k) s = fmaf(whh1[g][k], h1v[k], s);       \
            a[g] = s;                                                           \
        }                                                                       \
        _Pragma("unroll")                                                       \
        for (int g = 0; g < 4; ++g) {                                           \
            float s = a[g];                                                     \
            _Pragma("unroll")                                                   \
            for (int k = 0; k < 10; ++k) s = fmaf(wih1[g][k], h0v[k], s);       \
            a[g] = s;                                                           \
        }                                                                       \
        float i1 = sigm(a[0]), f1 = sigm(a[1]);                                 \
        float g1 = tanh_(a[2]), o1 = sigm(a[3]);                                \
        c1 = fmaf(f1, c1, i1 * g1);                                             \
        h1j = o1 * tanh_(c1);                                                   \
        _Pragma("unroll")                                                       \
        for (int k = 0; k < 10; ++k) h1v[k] = __shfl(h1j, k, 16);               \
    }

    for (int t0 = 0; t0 < 512; t0 += 4) {
        STEP(xb0, t0 + 4)
        STEP(xb1, t0 + 5)
        STEP(xb2, t0 + 6)
        STEP(xb3, t0 + 7)
    }
#undef STEP

    // ---- outputs ----
    // out layout: [0,4096) regression | [4096,+81920) hidden l0,l1 | then cell l0,l1
    float p = act ? h1j * wfc : 0.0f;
    #pragma unroll
    for (int off = 8; off > 0; off >>= 1) p += __shfl_xor(p, off, 16);
    if (l16 == 0) out[e] = p + bfc[0];
    if (act) {
        out[4096           + e * 10 + l16] = h0j;
        out[4096 + 40960   + e * 10 + l16] = h1j;
        out[4096 + 81920   + e * 10 + l16] = c0;
        out[4096 + 122880  + e * 10 + l16] = c1;
    }
}

extern "C" void kernel_launch(void* const* d_in, const int* in_sizes, int n_in,
                              void* d_out, int out_size, void* d_ws, size_t ws_size,
                              hipStream_t stream) {
    const float* x    = (const float*)d_in[0];
    const float* hid  = (const float*)d_in[1];
    const float* cel  = (const float*)d_in[2];
    const float* Wih0 = (const float*)d_in[3];
    const float* Whh0 = (const float*)d_in[4];
    const float* bih0 = (const float*)d_in[5];
    const float* bhh0 = (const float*)d_in[6];
    const float* Wih1 = (const float*)d_in[7];
    const float* Whh1 = (const float*)d_in[8];
    const float* bih1 = (const float*)d_in[9];
    const float* bhh1 = (const float*)d_in[10];
    const float* Wfc  = (const float*)d_in[11];
    const float* bfc  = (const float*)d_in[12];

    hipLaunchKernelGGL(lstm2_kernel, dim3(256), dim3(256), 0, stream,
                       x, hid, cel, Wih0, Whh0, bih0, bhh0,
                       Wih1, Whh1, bih1, bhh1, Wfc, bfc,
                       (float*)d_out);
}

// Round 2
// 274.409 us; speedup vs baseline: 1.1333x; 1.1333x over previous
//
#include <hip/hip_runtime.h>

// 2-layer LSTM, B=4096, S=512, F=8, H=10 + FC(10->1) on last step.
// R1: producer-consumer wave specialization. Waves 0-1 of each block run
// layer 0, waves 2-3 run layer 1 one timestep behind, h0 handed through a
// 2-slot LDS buffer with one __syncthreads per step. 512 blocks x 256 thr
// = 2048 waves = 2/SIMD (vs 1/SIMD in R0) at the SAME total instruction
// count -> stalls of one wave hidden by the other.
// Layout within a wave: 16 lanes per batch element (lane = hidden unit,
// 10 active), 4 elements per wave. Weights register-resident; both layers
// unified to inDim=10 (L0 input padded with zero weights).

#define L2E 1.4426950408889634f

__device__ __forceinline__ float sigm(float z) {
    return __builtin_amdgcn_rcpf(1.0f + __builtin_amdgcn_exp2f(-L2E * z));
}
__device__ __forceinline__ float tanh_(float z) {
    return 1.0f - 2.0f * __builtin_amdgcn_rcpf(1.0f + __builtin_amdgcn_exp2f((2.0f * L2E) * z));
}

__global__ __launch_bounds__(256, 2)
void lstm2_pipe(const float* __restrict__ x,
                const float* __restrict__ hid,
                const float* __restrict__ cel,
                const float* __restrict__ Wih0, const float* __restrict__ Whh0,
                const float* __restrict__ bih0, const float* __restrict__ bhh0,
                const float* __restrict__ Wih1, const float* __restrict__ Whh1,
                const float* __restrict__ bih1, const float* __restrict__ bhh1,
                const float* __restrict__ Wfc,  const float* __restrict__ bfc,
                float* __restrict__ out)
{
    __shared__ float h0buf[2][8][10];   // [slot][elemInBlock][unit], 640 B

    const int tid   = threadIdx.x;
    const int wid   = tid >> 6;
    const bool isL0 = (wid < 2);
    const int l16   = tid & 15;
    const int grp   = (tid & 63) >> 4;
    const int eIB   = ((wid & 1) << 2) + grp;   // element in block, 0..7
    const int e     = blockIdx.x * 8 + eIB;     // batch element
    const int j     = (l16 < 10) ? l16 : 0;
    const bool act  = (l16 < 10);

    // ---- register-resident weights (rows j, 10+j, 20+j, 30+j of this wave's layer) ----
    float wA[4][10], wB[4][10], bb[4];   // wA = recurrent, wB = input
    #pragma unroll
    for (int g = 0; g < 4; ++g) {
        const int r = g * 10 + j;
        if (isL0) {
            #pragma unroll
            for (int k = 0; k < 8; ++k) wB[g][k] = Wih0[r * 8 + k];
            wB[g][8] = 0.0f; wB[g][9] = 0.0f;
            #pragma unroll
            for (int k = 0; k < 10; ++k) wA[g][k] = Whh0[r * 10 + k];
            bb[g] = bih0[r] + bhh0[r];
        } else {
            #pragma unroll
            for (int k = 0; k < 10; ++k) wB[g][k] = Wih1[r * 10 + k];
            #pragma unroll
            for (int k = 0; k < 10; ++k) wA[g][k] = Whh1[r * 10 + k];
            bb[g] = bih1[r] + bhh1[r];
        }
    }
    const float wfc = (!isL0 && act) ? Wfc[j] : 0.0f;

    // ---- initial state (layer 0 or 1 per wave type) ----
    const int sbase = isL0 ? 0 : 40960;
    float hv[10];
    #pragma unroll
    for (int k = 0; k < 10; ++k) hv[k] = hid[sbase + e * 10 + k];
    float cc = cel[sbase + e * 10 + j];
    float hj = hv[j];

    const float4* __restrict__ xp = reinterpret_cast<const float4*>(x + (size_t)e * 4096);
    float4 xbA[2], xbB[2];
    if (isL0) {
        xbA[0] = xp[0]; xbA[1] = xp[1];   // x[0]
        xbB[0] = xp[2]; xbB[1] = xp[3];   // x[1]
    }

// Unified step: L0 waves read input from x-prefetch regs (padded to 10),
// L1 waves read h0 from LDS slot SLOTR. Recurrent dot first (hides LDS
// read latency), then input dot, activations, LDS write (L0), h-broadcast.
#define STEP(XB, TNEXT, SLOTW, SLOTR)                                        \
    {                                                                        \
        float in[10];                                                        \
        if (isL0) {                                                          \
            in[0] = XB[0].x; in[1] = XB[0].y; in[2] = XB[0].z; in[3] = XB[0].w; \
            in[4] = XB[1].x; in[5] = XB[1].y; in[6] = XB[1].z; in[7] = XB[1].w; \
            in[8] = 0.0f; in[9] = 0.0f;                                      \
            int tn = (TNEXT) > 511 ? 511 : (TNEXT);                          \
            XB[0] = xp[2 * tn]; XB[1] = xp[2 * tn + 1];                      \
        } else {                                                             \
            _Pragma("unroll")                                                \
            for (int k = 0; k < 10; ++k) in[k] = h0buf[SLOTR][eIB][k];       \
        }                                                                    \
        float a[4];                                                          \
        _Pragma("unroll")                                                    \
        for (int g = 0; g < 4; ++g) {                                        \
            float s = bb[g];                                                 \
            _Pragma("unroll")                                                \
            for (int k = 0; k < 10; ++k) s = fmaf(wA[g][k], hv[k], s);       \
            a[g] = s;                                                        \
        }                                                                    \
        _Pragma("unroll")                                                    \
        for (int g = 0; g < 4; ++g) {                                        \
            float s = a[g];                                                  \
            _Pragma("unroll")                                                \
            for (int k = 0; k < 10; ++k) s = fmaf(wB[g][k], in[k], s);       \
            a[g] = s;                                                        \
        }                                                                    \
        float i_ = sigm(a[0]), f_ = sigm(a[1]);                              \
        float g_ = tanh_(a[2]), o_ = sigm(a[3]);                             \
        cc = fmaf(f_, cc, i_ * g_);                                          \
        hj = o_ * tanh_(cc);                                                 \
        if (isL0 && act) h0buf[SLOTW][eIB][l16] = hj;                        \
        _Pragma("unroll")                                                    \
        for (int k = 0; k < 10; ++k) hv[k] = __shfl(hj, k, 16);              \
    }

    // iter 0: L0 computes step 0 -> slot 0; L1 idle
    if (isL0) STEP(xbA, 2, 0, 0)
    __syncthreads();
    // iters 1..510: L0 step k -> slot k&1; L1 step k-1 <- slot (k-1)&1
    for (int k = 1; k < 511; k += 2) {
        STEP(xbB, k + 2, 1, 0)     // k odd:  L0 step k (slot1); L1 step k-1 (slot0)
        __syncthreads();
        STEP(xbA, k + 3, 0, 1)     // k+1 even: L0 step k+1 (slot0); L1 step k (slot1)
        __syncthreads();
    }
    // iter 511: L0 step 511 -> slot 1; L1 step 510 <- slot 0
    STEP(xbB, 511, 1, 0)
    __syncthreads();
    // iter 512: L1 step 511 <- slot 1
    if (!isL0) STEP(xbA, 511, 0, 1)

#undef STEP

    // ---- outputs: [0,4096) fc | [+81920) hidden l0,l1 | [+81920) cell l0,l1 ----
    if (isL0) {
        if (act) {
            out[4096          + e * 10 + l16] = hj;   // h0_T
            out[4096 + 81920  + e * 10 + l16] = cc;   // c0_T
        }
    } else {
        float p = act ? hj * wfc : 0.0f;
        #pragma unroll
        for (int off = 8; off > 0; off >>= 1) p += __shfl_xor(p, off, 16);
        if (l16 == 0) out[e] = p + bfc[0];
        if (act) {
            out[4096 + 40960  + e * 10 + l16] = hj;   // h1_T
            out[4096 + 122880 + e * 10 + l16] = cc;   // c1_T
        }
    }
}

extern "C" void kernel_launch(void* const* d_in, const int* in_sizes, int n_in,
                              void* d_out, int out_size, void* d_ws, size_t ws_size,
                              hipStream_t stream) {
    const float* x    = (const float*)d_in[0];
    const float* hid  = (const float*)d_in[1];
    const float* cel  = (const float*)d_in[2];
    const float* Wih0 = (const float*)d_in[3];
    const float* Whh0 = (const float*)d_in[4];
    const float* bih0 = (const float*)d_in[5];
    const float* bhh0 = (const float*)d_in[6];
    const float* Wih1 = (const float*)d_in[7];
    const float* Whh1 = (const float*)d_in[8];
    const float* bih1 = (const float*)d_in[9];
    const float* bhh1 = (const float*)d_in[10];
    const float* Wfc  = (const float*)d_in[11];
    const float* bfc  = (const float*)d_in[12];

    hipLaunchKernelGGL(lstm2_pipe, dim3(512), dim3(256), 0, stream,
                       x, hid, cel, Wih0, Whh0, bih0, bhh0,
                       Wih1, Whh1, bih1, bhh1, Wfc, bfc,
                       (float*)d_out);
}

// Round 3
// 229.524 us; speedup vs baseline: 1.3549x; 1.1956x over previous
//
#include <hip/hip_runtime.h>

// 2-layer LSTM, B=4096, S=512, F=8, H=10 + FC(10->1) on last step.
// R2: R1's producer-consumer wave pipeline (L0 waves / L1 waves, LDS handoff)
// + packed fp32 dot products (float2 -> v_pk_fma_f32) halving FMA issue
// + h-broadcast via LDS write1/read5xb64 with immediate offsets (replaces
//   10 __shfl = 10 ds_bpermute + ~35 VALU of lane-index math per step)
// + 2 steps per __syncthreads (4-slot h0 double-double buffer), 256 barriers.
// 512 blocks x 256 thr = 2048 waves = 2/SIMD.

typedef float v2f __attribute__((ext_vector_type(2)));

#define L2E 1.4426950408889634f

__device__ __forceinline__ float sigm(float z) {
    return __builtin_amdgcn_rcpf(1.0f + __builtin_amdgcn_exp2f(-L2E * z));
}
__device__ __forceinline__ float tanh_(float z) {
    return 1.0f - 2.0f * __builtin_amdgcn_rcpf(1.0f + __builtin_amdgcn_exp2f((2.0f * L2E) * z));
}

__global__ __launch_bounds__(256, 2)
void lstm2_pk(const float* __restrict__ x,
              const float* __restrict__ hid,
              const float* __restrict__ cel,
              const float* __restrict__ Wih0, const float* __restrict__ Whh0,
              const float* __restrict__ bih0, const float* __restrict__ bhh0,
              const float* __restrict__ Wih1, const float* __restrict__ Whh1,
              const float* __restrict__ bih1, const float* __restrict__ bhh1,
              const float* __restrict__ Wfc,  const float* __restrict__ bfc,
              float* __restrict__ out)
{
    __shared__ float h0buf[4][8][10];   // 4 slots (t&3), 1280 B
    __shared__ float h1buf[8][10];      // L1 self-broadcast, 320 B

    const int tid   = threadIdx.x;
    const int wid   = tid >> 6;
    const bool isL0 = (wid < 2);
    const int l16   = tid & 15;
    const int grp   = (tid & 63) >> 4;
    const int eIB   = ((wid & 1) << 2) + grp;   // element in block, 0..7
    const int e     = blockIdx.x * 8 + eIB;     // batch element
    const int j     = (l16 < 10) ? l16 : 0;
    const bool act  = (l16 < 10);

    // ---- packed register-resident weights (rows j,10+j,20+j,30+j of this wave's layer) ----
    v2f wA2[4][5], wB2[4][5];   // wA2 = recurrent, wB2 = input
    float bb[4];
    #pragma unroll
    for (int g = 0; g < 4; ++g) {
        const int r = g * 10 + j;
        if (isL0) {
            #pragma unroll
            for (int k = 0; k < 4; ++k) { wB2[g][k].x = Wih0[r*8 + 2*k]; wB2[g][k].y = Wih0[r*8 + 2*k+1]; }
            wB2[g][4].x = 0.0f; wB2[g][4].y = 0.0f;
            #pragma unroll
            for (int k = 0; k < 5; ++k) { wA2[g][k].x = Whh0[r*10 + 2*k]; wA2[g][k].y = Whh0[r*10 + 2*k+1]; }
            bb[g] = bih0[r] + bhh0[r];
        } else {
            #pragma unroll
            for (int k = 0; k < 5; ++k) { wB2[g][k].x = Wih1[r*10 + 2*k]; wB2[g][k].y = Wih1[r*10 + 2*k+1]; }
            #pragma unroll
            for (int k = 0; k < 5; ++k) { wA2[g][k].x = Whh1[r*10 + 2*k]; wA2[g][k].y = Whh1[r*10 + 2*k+1]; }
            bb[g] = bih1[r] + bhh1[r];
        }
    }
    const float wfc = (!isL0 && act) ? Wfc[j] : 0.0f;

    // ---- initial state ----
    const int sbase = isL0 ? 0 : 40960;
    v2f hv2[5];
    #pragma unroll
    for (int k = 0; k < 5; ++k) { hv2[k].x = hid[sbase + e*10 + 2*k]; hv2[k].y = hid[sbase + e*10 + 2*k+1]; }
    float cc = cel[sbase + e * 10 + j];
    float hj = 0.0f;

    // ---- LDS row pointers (computed once; per-step reads use imm offsets) ----
    float* const self0 = isL0 ? &h0buf[0][eIB][0] : &h1buf[eIB][0];
    float* const self1 = isL0 ? &h0buf[1][eIB][0] : &h1buf[eIB][0];
    float* const self2 = isL0 ? &h0buf[2][eIB][0] : &h1buf[eIB][0];
    float* const self3 = isL0 ? &h0buf[3][eIB][0] : &h1buf[eIB][0];
    const v2f* const inrow0 = (const v2f*)&h0buf[0][eIB][0];
    const v2f* const inrow1 = (const v2f*)&h0buf[1][eIB][0];
    const v2f* const inrow2 = (const v2f*)&h0buf[2][eIB][0];
    const v2f* const inrow3 = (const v2f*)&h0buf[3][eIB][0];

    const float4* __restrict__ xp = reinterpret_cast<const float4*>(x + (size_t)e * 4096);
    float4 xb0[2], xb1[2], xb2[2], xb3[2];
    if (isL0) {
        xb0[0] = xp[0]; xb0[1] = xp[1];
        xb1[0] = xp[2]; xb1[1] = xp[3];
        xb2[0] = xp[4]; xb2[1] = xp[5];
        xb3[0] = xp[6]; xb3[1] = xp[7];
    }

// One LSTM step. SW = slot this step writes/reads-back its own h (t&3 for L0).
// SR = slot L1 reads its input h0 from ((t-2)&3 of L1's step = SW^2).
// TN = x prefetch target step for L0 (clamped to 511).
#define STEP(XB, SW, SR, TN)                                                   \
    {                                                                          \
        v2f inv[5];                                                            \
        if (isL0) {                                                            \
            inv[0].x = XB[0].x; inv[0].y = XB[0].y;                            \
            inv[1].x = XB[0].z; inv[1].y = XB[0].w;                            \
            inv[2].x = XB[1].x; inv[2].y = XB[1].y;                            \
            inv[3].x = XB[1].z; inv[3].y = XB[1].w;                            \
            inv[4].x = 0.0f;    inv[4].y = 0.0f;                               \
            int tn = (TN) > 511 ? 511 : (TN);                                  \
            XB[0] = xp[2*tn]; XB[1] = xp[2*tn + 1];                            \
        } else {                                                               \
            inv[0] = inrow##SR[0]; inv[1] = inrow##SR[1];                      \
            inv[2] = inrow##SR[2]; inv[3] = inrow##SR[3];                      \
            inv[4] = inrow##SR[4];                                             \
        }                                                                      \
        float aa[4];                                                           \
        _Pragma("unroll")                                                      \
        for (int g = 0; g < 4; ++g) {                                          \
            v2f acc; acc.x = bb[g]; acc.y = 0.0f;                              \
            _Pragma("unroll")                                                  \
            for (int k = 0; k < 5; ++k)                                        \
                acc = __builtin_elementwise_fma(wA2[g][k], hv2[k], acc);       \
            _Pragma("unroll")                                                  \
            for (int k = 0; k < 5; ++k)                                        \
                acc = __builtin_elementwise_fma(wB2[g][k], inv[k], acc);       \
            aa[g] = acc.x + acc.y;                                             \
        }                                                                      \
        float i_ = sigm(aa[0]), f_ = sigm(aa[1]);                              \
        float g_ = tanh_(aa[2]), o_ = sigm(aa[3]);                             \
        cc = fmaf(f_, cc, i_ * g_);                                            \
        hj = o_ * tanh_(cc);                                                   \
        if (act) self##SW[l16] = hj;                                           \
        {                                                                      \
            const v2f* sr_ = (const v2f*)self##SW;                             \
            hv2[0] = sr_[0]; hv2[1] = sr_[1]; hv2[2] = sr_[2];                 \
            hv2[3] = sr_[3]; hv2[4] = sr_[4];                                  \
        }                                                                      \
    }

    // phase 0: L0 steps 0,1 -> slots 0,1
    if (isL0) { STEP(xb0, 0, 2, 4) STEP(xb1, 1, 3, 5) }
    __syncthreads();

    // phases 1..254 (127 iters x 2 phases): L0 steps 2..509, L1 steps 0..507
    for (int it = 0; it < 127; ++it) {
        const int tb = 4 * it;
        STEP(xb2, 2, 0, tb + 6)      // L0 t=tb+2 ; L1 t=tb
        STEP(xb3, 3, 1, tb + 7)      // L0 t=tb+3 ; L1 t=tb+1
        __syncthreads();
        STEP(xb0, 0, 2, tb + 8)      // L0 t=tb+4 ; L1 t=tb+2
        STEP(xb1, 1, 3, tb + 9)      // L0 t=tb+5 ; L1 t=tb+3
        __syncthreads();
    }

    // phase 255: L0 steps 510,511 ; L1 steps 508,509
    STEP(xb2, 2, 0, 511)
    STEP(xb3, 3, 1, 511)
    __syncthreads();

    // phase 256: L1 steps 510,511 (reads slots 2,3)
    if (!isL0) { STEP(xb0, 0, 2, 511) STEP(xb1, 1, 3, 511) }

#undef STEP

    // ---- outputs: [0,4096) fc | hidden l0,l1 | cell l0,l1 ----
    if (isL0) {
        if (act) {
            out[4096          + e * 10 + l16] = hj;   // h0_T
            out[4096 + 81920  + e * 10 + l16] = cc;   // c0_T
        }
    } else {
        float p = act ? hj * wfc : 0.0f;
        #pragma unroll
        for (int off = 8; off > 0; off >>= 1) p += __shfl_xor(p, off, 16);
        if (l16 == 0) out[e] = p + bfc[0];
        if (act) {
            out[4096 + 40960  + e * 10 + l16] = hj;   // h1_T
            out[4096 + 122880 + e * 10 + l16] = cc;   // c1_T
        }
    }
}

extern "C" void kernel_launch(void* const* d_in, const int* in_sizes, int n_in,
                              void* d_out, int out_size, void* d_ws, size_t ws_size,
                              hipStream_t stream) {
    const float* x    = (const float*)d_in[0];
    const float* hid  = (const float*)d_in[1];
    const float* cel  = (const float*)d_in[2];
    const float* Wih0 = (const float*)d_in[3];
    const float* Whh0 = (const float*)d_in[4];
    const float* bih0 = (const float*)d_in[5];
    const float* bhh0 = (const float*)d_in[6];
    const float* Wih1 = (const float*)d_in[7];
    const float* Whh1 = (const float*)d_in[8];
    const float* bih1 = (const float*)d_in[9];
    const float* bhh1 = (const float*)d_in[10];
    const float* Wfc  = (const float*)d_in[11];
    const float* bfc  = (const float*)d_in[12];

    hipLaunchKernelGGL(lstm2_pk, dim3(512), dim3(256), 0, stream,
                       x, hid, cel, Wih0, Whh0, bih0, bhh0,
                       Wih1, Whh1, bih1, bhh1, Wfc, bfc,
                       (float*)d_out);
}

// Round 4
// 204.300 us; speedup vs baseline: 1.5222x; 1.1235x over previous
//
#include <hip/hip_runtime.h>

// 2-layer LSTM, B=4096, S=512, F=8, H=10 + FC(10->1) on last step.
// R3: fully-specialized producer/consumer wave paths. Wave role (L0 vs L1)
// is scalarized via readfirstlane -> one s_cbranch at top; L0 waves and L1
// waves execute disjoint instruction streams (R2 predicated BOTH paths in
// every wave: ~197 VALU/step measured vs ~85 intended).
// L0 waves: steps 0..511 feeding h0 into a 4-slot LDS buffer, 2 steps per
// barrier. L1 waves: 2 steps behind, reading slots. 256 barriers each side
// (AMD s_barrier counts arriving waves; divergent placement is fine).
// Packed fp32 (v_pk_fma_f32) dots; h self-broadcast via LDS row write+readback.
// 512 blocks x 256 thr = 2048 waves = 2/SIMD.

typedef float v2f __attribute__((ext_vector_type(2)));

#define L2E 1.4426950408889634f

__device__ __forceinline__ float sigm(float z) {
    return __builtin_amdgcn_rcpf(1.0f + __builtin_amdgcn_exp2f(-L2E * z));
}
__device__ __forceinline__ float tanh_(float z) {
    return 1.0f - 2.0f * __builtin_amdgcn_rcpf(1.0f + __builtin_amdgcn_exp2f((2.0f * L2E) * z));
}

__global__ __launch_bounds__(256, 2)
void lstm2_spec(const float* __restrict__ x,
                const float* __restrict__ hid,
                const float* __restrict__ cel,
                const float* __restrict__ Wih0, const float* __restrict__ Whh0,
                const float* __restrict__ bih0, const float* __restrict__ bhh0,
                const float* __restrict__ Wih1, const float* __restrict__ Whh1,
                const float* __restrict__ bih1, const float* __restrict__ bhh1,
                const float* __restrict__ Wfc,  const float* __restrict__ bfc,
                float* __restrict__ out)
{
    __shared__ float h0buf[4][8][10];   // 4 slots (t&3), 1280 B
    __shared__ float h1buf[8][10];      // L1 self-broadcast rows, 320 B

    const int tid  = threadIdx.x;
    const int wid  = tid >> 6;
    const int uwid = __builtin_amdgcn_readfirstlane(wid);  // scalar wave role
    const int l16  = tid & 15;
    const int grp  = (tid & 63) >> 4;
    const int eIB  = ((wid & 1) << 2) + grp;   // element in block, 0..7
    const int e    = blockIdx.x * 8 + eIB;     // batch element
    const int j    = (l16 < 10) ? l16 : 0;
    const bool act = (l16 < 10);

    if (uwid < 2) {
        // ================= LAYER-0 (producer) waves =================
        v2f wA2[4][5], wx2[4][4];  float bb[4];
        #pragma unroll
        for (int g = 0; g < 4; ++g) {
            const int r = g * 10 + j;
            #pragma unroll
            for (int k = 0; k < 5; ++k) { wA2[g][k].x = Whh0[r*10 + 2*k]; wA2[g][k].y = Whh0[r*10 + 2*k+1]; }
            #pragma unroll
            for (int k = 0; k < 4; ++k) { wx2[g][k].x = Wih0[r*8 + 2*k];  wx2[g][k].y = Wih0[r*8 + 2*k+1]; }
            bb[g] = bih0[r] + bhh0[r];
        }
        v2f hv2[5];
        #pragma unroll
        for (int k = 0; k < 5; ++k) { hv2[k].x = hid[e*10 + 2*k]; hv2[k].y = hid[e*10 + 2*k+1]; }
        float cc = cel[e * 10 + j];
        float hj = 0.0f;

        float* const wrow0 = &h0buf[0][eIB][0];
        float* const wrow1 = &h0buf[1][eIB][0];
        float* const wrow2 = &h0buf[2][eIB][0];
        float* const wrow3 = &h0buf[3][eIB][0];

        const float4* __restrict__ xp = reinterpret_cast<const float4*>(x + (size_t)e * 4096);
        float4 xb0[2], xb1[2], xb2[2], xb3[2];
        xb0[0] = xp[0]; xb0[1] = xp[1];
        xb1[0] = xp[2]; xb1[1] = xp[3];
        xb2[0] = xp[4]; xb2[1] = xp[5];
        xb3[0] = xp[6]; xb3[1] = xp[7];

#define L0STEP(XB, SW, TN)                                                   \
        {                                                                    \
            v2f xin0, xin1, xin2, xin3;                                      \
            xin0.x = XB[0].x; xin0.y = XB[0].y;                              \
            xin1.x = XB[0].z; xin1.y = XB[0].w;                              \
            xin2.x = XB[1].x; xin2.y = XB[1].y;                              \
            xin3.x = XB[1].z; xin3.y = XB[1].w;                              \
            { int tn = (TN) > 511 ? 511 : (TN);                              \
              XB[0] = xp[2*tn]; XB[1] = xp[2*tn + 1]; }                      \
            float aa[4];                                                     \
            _Pragma("unroll")                                                \
            for (int g = 0; g < 4; ++g) {                                    \
                v2f acc; acc.x = bb[g]; acc.y = 0.0f;                        \
                acc = __builtin_elementwise_fma(wA2[g][0], hv2[0], acc);     \
                acc = __builtin_elementwise_fma(wA2[g][1], hv2[1], acc);     \
                acc = __builtin_elementwise_fma(wA2[g][2], hv2[2], acc);     \
                acc = __builtin_elementwise_fma(wA2[g][3], hv2[3], acc);     \
                acc = __builtin_elementwise_fma(wA2[g][4], hv2[4], acc);     \
                acc = __builtin_elementwise_fma(wx2[g][0], xin0, acc);       \
                acc = __builtin_elementwise_fma(wx2[g][1], xin1, acc);       \
                acc = __builtin_elementwise_fma(wx2[g][2], xin2, acc);       \
                acc = __builtin_elementwise_fma(wx2[g][3], xin3, acc);       \
                aa[g] = acc.x + acc.y;                                       \
            }                                                                \
            float i_ = sigm(aa[0]), f_ = sigm(aa[1]);                        \
            float g_ = tanh_(aa[2]), o_ = sigm(aa[3]);                       \
            cc = fmaf(f_, cc, i_ * g_);                                      \
            hj = o_ * tanh_(cc);                                             \
            if (act) wrow##SW[l16] = hj;                                     \
            { const v2f* rb_ = (const v2f*)wrow##SW;                         \
              hv2[0] = rb_[0]; hv2[1] = rb_[1]; hv2[2] = rb_[2];             \
              hv2[3] = rb_[3]; hv2[4] = rb_[4]; }                            \
        }

        for (int it = 0; it < 128; ++it) {
            const int tb = 4 * it;
            L0STEP(xb0, 0, tb + 4)
            L0STEP(xb1, 1, tb + 5)
            __syncthreads();
            L0STEP(xb2, 2, tb + 6)
            L0STEP(xb3, 3, tb + 7)
            __syncthreads();
        }
#undef L0STEP

        if (act) {
            out[4096          + e * 10 + l16] = hj;   // h0_T
            out[4096 + 81920  + e * 10 + l16] = cc;   // c0_T
        }

    } else {
        // ================= LAYER-1 (consumer) waves =================
        v2f wA2[4][5], wB2[4][5];  float bb[4];
        #pragma unroll
        for (int g = 0; g < 4; ++g) {
            const int r = g * 10 + j;
            #pragma unroll
            for (int k = 0; k < 5; ++k) { wA2[g][k].x = Whh1[r*10 + 2*k]; wA2[g][k].y = Whh1[r*10 + 2*k+1]; }
            #pragma unroll
            for (int k = 0; k < 5; ++k) { wB2[g][k].x = Wih1[r*10 + 2*k]; wB2[g][k].y = Wih1[r*10 + 2*k+1]; }
            bb[g] = bih1[r] + bhh1[r];
        }
        const float wfc = act ? Wfc[j] : 0.0f;
        v2f hv2[5];
        #pragma unroll
        for (int k = 0; k < 5; ++k) { hv2[k].x = hid[40960 + e*10 + 2*k]; hv2[k].y = hid[40960 + e*10 + 2*k+1]; }
        float cc = cel[40960 + e * 10 + j];
        float hj = 0.0f;

        float* const h1row = &h1buf[eIB][0];
        const v2f* const irow0 = (const v2f*)&h0buf[0][eIB][0];
        const v2f* const irow1 = (const v2f*)&h0buf[1][eIB][0];
        const v2f* const irow2 = (const v2f*)&h0buf[2][eIB][0];
        const v2f* const irow3 = (const v2f*)&h0buf[3][eIB][0];

#define L1STEP(SR)                                                           \
        {                                                                    \
            v2f in0 = irow##SR[0], in1 = irow##SR[1], in2 = irow##SR[2],     \
                in3 = irow##SR[3], in4 = irow##SR[4];                        \
            float aa[4];                                                     \
            _Pragma("unroll")                                                \
            for (int g = 0; g < 4; ++g) {                                    \
                v2f acc; acc.x = bb[g]; acc.y = 0.0f;                        \
                acc = __builtin_elementwise_fma(wA2[g][0], hv2[0], acc);     \
                acc = __builtin_elementwise_fma(wA2[g][1], hv2[1], acc);     \
                acc = __builtin_elementwise_fma(wA2[g][2], hv2[2], acc);     \
                acc = __builtin_elementwise_fma(wA2[g][3], hv2[3], acc);     \
                acc = __builtin_elementwise_fma(wA2[g][4], hv2[4], acc);     \
                acc = __builtin_elementwise_fma(wB2[g][0], in0, acc);        \
                acc = __builtin_elementwise_fma(wB2[g][1], in1, acc);        \
                acc = __builtin_elementwise_fma(wB2[g][2], in2, acc);        \
                acc = __builtin_elementwise_fma(wB2[g][3], in3, acc);        \
                acc = __builtin_elementwise_fma(wB2[g][4], in4, acc);        \
                aa[g] = acc.x + acc.y;                                       \
            }                                                                \
            float i_ = sigm(aa[0]), f_ = sigm(aa[1]);                        \
            float g_ = tanh_(aa[2]), o_ = sigm(aa[3]);                       \
            cc = fmaf(f_, cc, i_ * g_);                                      \
            hj = o_ * tanh_(cc);                                             \
            if (act) h1row[l16] = hj;                                        \
            { const v2f* rb_ = (const v2f*)h1row;                            \
              hv2[0] = rb_[0]; hv2[1] = rb_[1]; hv2[2] = rb_[2];             \
              hv2[3] = rb_[3]; hv2[4] = rb_[4]; }                            \
        }

        for (int it = 0; it < 128; ++it) {
            __syncthreads();
            L1STEP(0)
            L1STEP(1)
            __syncthreads();
            L1STEP(2)
            L1STEP(3)
        }
#undef L1STEP

        float p = act ? hj * wfc : 0.0f;
        #pragma unroll
        for (int off = 8; off > 0; off >>= 1) p += __shfl_xor(p, off, 16);
        if (l16 == 0) out[e] = p + bfc[0];
        if (act) {
            out[4096 + 40960  + e * 10 + l16] = hj;   // h1_T
            out[4096 + 122880 + e * 10 + l16] = cc;   // c1_T
        }
    }
}

extern "C" void kernel_launch(void* const* d_in, const int* in_sizes, int n_in,
                              void* d_out, int out_size, void* d_ws, size_t ws_size,
                              hipStream_t stream) {
    const float* x    = (const float*)d_in[0];
    const float* hid  = (const float*)d_in[1];
    const float* cel  = (const float*)d_in[2];
    const float* Wih0 = (const float*)d_in[3];
    const float* Whh0 = (const float*)d_in[4];
    const float* bih0 = (const float*)d_in[5];
    const float* bhh0 = (const float*)d_in[6];
    const float* Wih1 = (const float*)d_in[7];
    const float* Whh1 = (const float*)d_in[8];
    const float* bih1 = (const float*)d_in[9];
    const float* bhh1 = (const float*)d_in[10];
    const float* Wfc  = (const float*)d_in[11];
    const float* bfc  = (const float*)d_in[12];

    hipLaunchKernelGGL(lstm2_spec, dim3(512), dim3(256), 0, stream,
                       x, hid, cel, Wih0, Whh0, bih0, bhh0,
                       Wih1, Whh1, bih1, bhh1, Wfc, bfc,
                       (float*)d_out);
}

// Round 5
// 203.809 us; speedup vs baseline: 1.5259x; 1.0024x over previous
//
#include <hip/hip_runtime.h>

// 2-layer LSTM, B=4096, S=512, F=8, H=10 + FC(10->1) on last step.
// R4: specialized producer/consumer waves (R3) +
//  - L2E folded into weights/biases (2*L2E for g-gate) -> activations are
//    rcp(1+exp2(+/-a)) with free neg input modifier; no per-act muls
//  - scalar v_fma_f32 dots (pk_fma is 4cyc = no fp32 throughput gain; scalar
//    kills the v2f packing movs + finalize adds)
//  - step reordered: load-independent dot first so the h LDS readback issued
//    at the previous step's end lands under FMA work (no lgkm stall)
//  - 8-slot h0 buffer, one barrier per 4 steps (128 barriers vs 256)
// 512 blocks x 256 thr = 2048 waves = 2/SIMD.

typedef float v2f __attribute__((ext_vector_type(2)));

#define L2E 1.4426950408889634f

__global__ __launch_bounds__(256, 2)
void lstm2_r4(const float* __restrict__ x,
              const float* __restrict__ hid,
              const float* __restrict__ cel,
              const float* __restrict__ Wih0, const float* __restrict__ Whh0,
              const float* __restrict__ bih0, const float* __restrict__ bhh0,
              const float* __restrict__ Wih1, const float* __restrict__ Whh1,
              const float* __restrict__ bih1, const float* __restrict__ bhh1,
              const float* __restrict__ Wfc,  const float* __restrict__ bfc,
              float* __restrict__ out)
{
    __shared__ float h0buf[8][8][10];   // 8 slots (t&7), 2560 B
    __shared__ float h1buf[8][10];      // L1 self-broadcast rows, 320 B

    const int tid  = threadIdx.x;
    const int wid  = tid >> 6;
    const int uwid = __builtin_amdgcn_readfirstlane(wid);  // scalar wave role
    const int l16  = tid & 15;
    const int grp  = (tid & 63) >> 4;
    const int eIB  = ((wid & 1) << 2) + grp;   // element in block, 0..7
    const int e    = blockIdx.x * 8 + eIB;     // batch element
    const int j    = (l16 < 10) ? l16 : 0;
    const bool act = (l16 < 10);

// activation helpers on pre-scaled args (a = L2E*z for sigm, 2*L2E*z for tanh)
#define SIGM(a)  __builtin_amdgcn_rcpf(1.0f + __builtin_amdgcn_exp2f(-(a)))
#define TANHP(a) fmaf(-2.0f, __builtin_amdgcn_rcpf(1.0f + __builtin_amdgcn_exp2f(a)), 1.0f)

    if (uwid < 2) {
        // ================= LAYER-0 (producer) waves =================
        float wA[4][10], wx[4][8], bb[4];
        #pragma unroll
        for (int g = 0; g < 4; ++g) {
            const int r = g * 10 + j;
            const float sc = (g == 2) ? 2.0f * L2E : L2E;
            #pragma unroll
            for (int k = 0; k < 10; ++k) wA[g][k] = Whh0[r*10 + k] * sc;
            #pragma unroll
            for (int k = 0; k < 8; ++k)  wx[g][k] = Wih0[r*8 + k] * sc;
            bb[g] = (bih0[r] + bhh0[r]) * sc;
        }
        float hv[10];
        #pragma unroll
        for (int k = 0; k < 10; ++k) hv[k] = hid[e*10 + k];
        float cc = cel[e * 10 + j];
        float hj = 0.0f;

        float* const wbase = &h0buf[0][eIB][0];   // slot stride 80 floats

        const float4* __restrict__ xp = reinterpret_cast<const float4*>(x + (size_t)e * 4096);
        float4 xb0[2], xb1[2], xb2[2], xb3[2];
        xb0[0] = xp[0]; xb0[1] = xp[1];
        xb1[0] = xp[2]; xb1[1] = xp[3];
        xb2[0] = xp[4]; xb2[1] = xp[5];
        xb3[0] = xp[6]; xb3[1] = xp[7];

#define L0STEP(XB, S, TN)                                                    \
        {                                                                    \
            float a0 = bb[0], a1 = bb[1], a2 = bb[2], a3 = bb[3];            \
            /* x-part first: no load dependency, covers h readback */        \
            a0 = fmaf(wx[0][0], XB[0].x, a0); a1 = fmaf(wx[1][0], XB[0].x, a1); \
            a2 = fmaf(wx[2][0], XB[0].x, a2); a3 = fmaf(wx[3][0], XB[0].x, a3); \
            a0 = fmaf(wx[0][1], XB[0].y, a0); a1 = fmaf(wx[1][1], XB[0].y, a1); \
            a2 = fmaf(wx[2][1], XB[0].y, a2); a3 = fmaf(wx[3][1], XB[0].y, a3); \
            a0 = fmaf(wx[0][2], XB[0].z, a0); a1 = fmaf(wx[1][2], XB[0].z, a1); \
            a2 = fmaf(wx[2][2], XB[0].z, a2); a3 = fmaf(wx[3][2], XB[0].z, a3); \
            a0 = fmaf(wx[0][3], XB[0].w, a0); a1 = fmaf(wx[1][3], XB[0].w, a1); \
            a2 = fmaf(wx[2][3], XB[0].w, a2); a3 = fmaf(wx[3][3], XB[0].w, a3); \
            a0 = fmaf(wx[0][4], XB[1].x, a0); a1 = fmaf(wx[1][4], XB[1].x, a1); \
            a2 = fmaf(wx[2][4], XB[1].x, a2); a3 = fmaf(wx[3][4], XB[1].x, a3); \
            a0 = fmaf(wx[0][5], XB[1].y, a0); a1 = fmaf(wx[1][5], XB[1].y, a1); \
            a2 = fmaf(wx[2][5], XB[1].y, a2); a3 = fmaf(wx[3][5], XB[1].y, a3); \
            a0 = fmaf(wx[0][6], XB[1].z, a0); a1 = fmaf(wx[1][6], XB[1].z, a1); \
            a2 = fmaf(wx[2][6], XB[1].z, a2); a3 = fmaf(wx[3][6], XB[1].z, a3); \
            a0 = fmaf(wx[0][7], XB[1].w, a0); a1 = fmaf(wx[1][7], XB[1].w, a1); \
            a2 = fmaf(wx[2][7], XB[1].w, a2); a3 = fmaf(wx[3][7], XB[1].w, a3); \
            { int tn = (TN) > 511 ? 511 : (TN);                              \
              XB[0] = xp[2*tn]; XB[1] = xp[2*tn + 1]; }                      \
            _Pragma("unroll")                                                \
            for (int k = 0; k < 10; ++k) {                                   \
                a0 = fmaf(wA[0][k], hv[k], a0);                              \
                a1 = fmaf(wA[1][k], hv[k], a1);                              \
                a2 = fmaf(wA[2][k], hv[k], a2);                              \
                a3 = fmaf(wA[3][k], hv[k], a3);                              \
            }                                                                \
            float i_ = SIGM(a0), f_ = SIGM(a1);                              \
            float g_ = TANHP(a2), o_ = SIGM(a3);                             \
            cc = fmaf(f_, cc, i_ * g_);                                      \
            float tc_ = (2.0f * L2E) * cc;                                   \
            hj = o_ * TANHP(tc_);                                            \
            if (act) wbase[(S)*80 + l16] = hj;                               \
            { const v2f* rb_ = (const v2f*)(wbase + (S)*80);                 \
              v2f r0_=rb_[0], r1_=rb_[1], r2_=rb_[2], r3_=rb_[3], r4_=rb_[4];\
              hv[0]=r0_.x; hv[1]=r0_.y; hv[2]=r1_.x; hv[3]=r1_.y;            \
              hv[4]=r2_.x; hv[5]=r2_.y; hv[6]=r3_.x; hv[7]=r3_.y;            \
              hv[8]=r4_.x; hv[9]=r4_.y; }                                    \
        }

        for (int it = 0; it < 64; ++it) {
            const int tb = 8 * it;
            L0STEP(xb0, 0, tb + 4)
            L0STEP(xb1, 1, tb + 5)
            L0STEP(xb2, 2, tb + 6)
            L0STEP(xb3, 3, tb + 7)
            __syncthreads();
            L0STEP(xb0, 4, tb + 8)
            L0STEP(xb1, 5, tb + 9)
            L0STEP(xb2, 6, tb + 10)
            L0STEP(xb3, 7, tb + 11)
            __syncthreads();
        }
#undef L0STEP

        if (act) {
            out[4096          + e * 10 + l16] = hj;   // h0_T
            out[4096 + 81920  + e * 10 + l16] = cc;   // c0_T
        }

    } else {
        // ================= LAYER-1 (consumer) waves =================
        float wA[4][10], wB[4][10], bb[4];
        #pragma unroll
        for (int g = 0; g < 4; ++g) {
            const int r = g * 10 + j;
            const float sc = (g == 2) ? 2.0f * L2E : L2E;
            #pragma unroll
            for (int k = 0; k < 10; ++k) wA[g][k] = Whh1[r*10 + k] * sc;
            #pragma unroll
            for (int k = 0; k < 10; ++k) wB[g][k] = Wih1[r*10 + k] * sc;
            bb[g] = (bih1[r] + bhh1[r]) * sc;
        }
        const float wfc = act ? Wfc[j] : 0.0f;
        float hv[10];
        #pragma unroll
        for (int k = 0; k < 10; ++k) hv[k] = hid[40960 + e*10 + k];
        float cc = cel[40960 + e * 10 + j];
        float hj = 0.0f;

        float* const h1w   = &h1buf[eIB][0];
        const float* const rbase = &h0buf[0][eIB][0];   // slot stride 80 floats

#define L1STEP(S)                                                            \
        {                                                                    \
            /* issue input reads at top; recurrent dot covers their latency */\
            const v2f* ir_ = (const v2f*)(rbase + (S)*80);                   \
            v2f i0_=ir_[0], i1_=ir_[1], i2_=ir_[2], i3_=ir_[3], i4_=ir_[4];  \
            float a0 = bb[0], a1 = bb[1], a2 = bb[2], a3 = bb[3];            \
            _Pragma("unroll")                                                \
            for (int k = 0; k < 10; ++k) {                                   \
                a0 = fmaf(wA[0][k], hv[k], a0);                              \
                a1 = fmaf(wA[1][k], hv[k], a1);                              \
                a2 = fmaf(wA[2][k], hv[k], a2);                              \
                a3 = fmaf(wA[3][k], hv[k], a3);                              \
            }                                                                \
            a0 = fmaf(wB[0][0], i0_.x, a0); a1 = fmaf(wB[1][0], i0_.x, a1);  \
            a2 = fmaf(wB[2][0], i0_.x, a2); a3 = fmaf(wB[3][0], i0_.x, a3);  \
            a0 = fmaf(wB[0][1], i0_.y, a0); a1 = fmaf(wB[1][1], i0_.y, a1);  \
            a2 = fmaf(wB[2][1], i0_.y, a2); a3 = fmaf(wB[3][1], i0_.y, a3);  \
            a0 = fmaf(wB[0][2], i1_.x, a0); a1 = fmaf(wB[1][2], i1_.x, a1);  \
            a2 = fmaf(wB[2][2], i1_.x, a2); a3 = fmaf(wB[3][2], i1_.x, a3);  \
            a0 = fmaf(wB[0][3], i1_.y, a0); a1 = fmaf(wB[1][3], i1_.y, a1);  \
            a2 = fmaf(wB[2][3], i1_.y, a2); a3 = fmaf(wB[3][3], i1_.y, a3);  \
            a0 = fmaf(wB[0][4], i2_.x, a0); a1 = fmaf(wB[1][4], i2_.x, a1);  \
            a2 = fmaf(wB[2][4], i2_.x, a2); a3 = fmaf(wB[3][4], i2_.x, a3);  \
            a0 = fmaf(wB[0][5], i2_.y, a0); a1 = fmaf(wB[1][5], i2_.y, a1);  \
            a2 = fmaf(wB[2][5], i2_.y, a2); a3 = fmaf(wB[3][5], i2_.y, a3);  \
            a0 = fmaf(wB[0][6], i3_.x, a0); a1 = fmaf(wB[1][6], i3_.x, a1);  \
            a2 = fmaf(wB[2][6], i3_.x, a2); a3 = fmaf(wB[3][6], i3_.x, a3);  \
            a0 = fmaf(wB[0][7], i3_.y, a0); a1 = fmaf(wB[1][7], i3_.y, a1);  \
            a2 = fmaf(wB[2][7], i3_.y, a2); a3 = fmaf(wB[3][7], i3_.y, a3);  \
            a0 = fmaf(wB[0][8], i4_.x, a0); a1 = fmaf(wB[1][8], i4_.x, a1);  \
            a2 = fmaf(wB[2][8], i4_.x, a2); a3 = fmaf(wB[3][8], i4_.x, a3);  \
            a0 = fmaf(wB[0][9], i4_.y, a0); a1 = fmaf(wB[1][9], i4_.y, a1);  \
            a2 = fmaf(wB[2][9], i4_.y, a2); a3 = fmaf(wB[3][9], i4_.y, a3);  \
            float i_ = SIGM(a0), f_ = SIGM(a1);                              \
            float g_ = TANHP(a2), o_ = SIGM(a3);                             \
            cc = fmaf(f_, cc, i_ * g_);                                      \
            float tc_ = (2.0f * L2E) * cc;                                   \
            hj = o_ * TANHP(tc_);                                            \
            if (act) h1w[l16] = hj;                                          \
            { const v2f* rb_ = (const v2f*)h1w;                              \
              v2f r0_=rb_[0], r1_=rb_[1], r2_=rb_[2], r3_=rb_[3], r4_=rb_[4];\
              hv[0]=r0_.x; hv[1]=r0_.y; hv[2]=r1_.x; hv[3]=r1_.y;            \
              hv[4]=r2_.x; hv[5]=r2_.y; hv[6]=r3_.x; hv[7]=r3_.y;            \
              hv[8]=r4_.x; hv[9]=r4_.y; }                                    \
        }

        for (int it = 0; it < 64; ++it) {
            __syncthreads();
            L1STEP(0)
            L1STEP(1)
            L1STEP(2)
            L1STEP(3)
            __syncthreads();
            L1STEP(4)
            L1STEP(5)
            L1STEP(6)
            L1STEP(7)
        }
#undef L1STEP

        float p = hj * wfc;
        #pragma unroll
        for (int off = 8; off > 0; off >>= 1) p += __shfl_xor(p, off, 16);
        if (l16 == 0) out[e] = p + bfc[0];
        if (act) {
            out[4096 + 40960  + e * 10 + l16] = hj;   // h1_T
            out[4096 + 122880 + e * 10 + l16] = cc;   // c1_T
        }
    }
}

extern "C" void kernel_launch(void* const* d_in, const int* in_sizes, int n_in,
                              void* d_out, int out_size, void* d_ws, size_t ws_size,
                              hipStream_t stream) {
    const float* x    = (const float*)d_in[0];
    const float* hid  = (const float*)d_in[1];
    const float* cel  = (const float*)d_in[2];
    const float* Wih0 = (const float*)d_in[3];
    const float* Whh0 = (const float*)d_in[4];
    const float* bih0 = (const float*)d_in[5];
    const float* bhh0 = (const float*)d_in[6];
    const float* Wih1 = (const float*)d_in[7];
    const float* Whh1 = (const float*)d_in[8];
    const float* bih1 = (const float*)d_in[9];
    const float* bhh1 = (const float*)d_in[10];
    const float* Wfc  = (const float*)d_in[11];
    const float* bfc  = (const float*)d_in[12];

    hipLaunchKernelGGL(lstm2_r4, dim3(512), dim3(256), 0, stream,
                       x, hid, cel, Wih0, Whh0, bih0, bhh0,
                       Wih1, Whh1, bih1, bhh1, Wfc, bfc,
                       (float*)d_out);
}

// Round 7
// 181.773 us; speedup vs baseline: 1.7108x; 1.1212x over previous
//
#include <hip/hip_runtime.h>

// 2-layer LSTM, B=4096, S=512, F=8, H=10 + FC(10->1) on last step.
// R6 (= R5 with compile fix): specialized producer/consumer waves + f16
// packed dots via v_dot2_f32_f16 (2 MAC / inst, f32 accumulate).
//  - v2h is __fp16 ext_vector_type(2) (what cvt_pkrtz returns and fdot2 takes)
//  - weights/h/x quantized to f16; gate accum, activations, cell state f32.
//  - h broadcast: ds_write_b16 + 5x half2 reads; rows padded to 16 halves.
// 512 blocks x 256 thr = 2048 waves = 2/SIMD.

typedef __fp16 v2h __attribute__((ext_vector_type(2)));

#define L2E 1.4426950408889634f

#define HAS_FDOT2 __has_builtin(__builtin_amdgcn_fdot2)

__device__ __forceinline__ v2h pkh(float a, float b) {
    return __builtin_amdgcn_cvt_pkrtz(a, b);
}

// activation helpers on pre-scaled args (a = L2E*z for sigm, 2*L2E*z for tanh)
#define SIGM(a)  __builtin_amdgcn_rcpf(1.0f + __builtin_amdgcn_exp2f(-(a)))
#define TANHP(a) fmaf(-2.0f, __builtin_amdgcn_rcpf(1.0f + __builtin_amdgcn_exp2f(a)), 1.0f)

#if HAS_FDOT2
#define DOT2(acc, w, v) (acc) = __builtin_amdgcn_fdot2((w), (v), (acc), false)
#else
#define DOT2(acc, w, v) (acc) = fmaf((float)(w).x, (float)(v).x, fmaf((float)(w).y, (float)(v).y, (acc)))
#endif

__global__ __launch_bounds__(256, 2)
void lstm2_r6(const float* __restrict__ x,
              const float* __restrict__ hid,
              const float* __restrict__ cel,
              const float* __restrict__ Wih0, const float* __restrict__ Whh0,
              const float* __restrict__ bih0, const float* __restrict__ bhh0,
              const float* __restrict__ Wih1, const float* __restrict__ Whh1,
              const float* __restrict__ bih1, const float* __restrict__ bhh1,
              const float* __restrict__ Wfc,  const float* __restrict__ bfc,
              float* __restrict__ out)
{
    __shared__ __fp16 h0buf[8][8][16];   // 8 slots, rows padded to 16 halves (2 KB)
    __shared__ __fp16 h1buf[8][16];      // L1 self-broadcast rows (256 B)

    const int tid  = threadIdx.x;
    const int wid  = tid >> 6;
    const int uwid = __builtin_amdgcn_readfirstlane(wid);  // scalar wave role
    const int l16  = tid & 15;
    const int grp  = (tid & 63) >> 4;
    const int eIB  = ((wid & 1) << 2) + grp;   // element in block, 0..7
    const int e    = blockIdx.x * 8 + eIB;     // batch element
    const int j    = (l16 < 10) ? l16 : 0;
    const bool act = (l16 < 10);

    if (uwid < 2) {
        // ================= LAYER-0 (producer) waves =================
        v2h wA[4][5], wx[4][4];  float bb[4];
        #pragma unroll
        for (int g = 0; g < 4; ++g) {
            const int r = g * 10 + j;
            const float sc = (g == 2) ? 2.0f * L2E : L2E;
            #pragma unroll
            for (int k = 0; k < 5; ++k) wA[g][k] = pkh(Whh0[r*10 + 2*k] * sc, Whh0[r*10 + 2*k+1] * sc);
            #pragma unroll
            for (int k = 0; k < 4; ++k) wx[g][k] = pkh(Wih0[r*8 + 2*k] * sc, Wih0[r*8 + 2*k+1] * sc);
            bb[g] = (bih0[r] + bhh0[r]) * sc;
        }
        v2h hv[5];
        #pragma unroll
        for (int k = 0; k < 5; ++k) hv[k] = pkh(hid[e*10 + 2*k], hid[e*10 + 2*k+1]);
        float cc = cel[e * 10 + j];
        float hj = 0.0f;

        __fp16* const wbase = &h0buf[0][eIB][0];   // slot stride 128 halves

        const float4* __restrict__ xp = reinterpret_cast<const float4*>(x + (size_t)e * 4096);
        float4 xb0[2], xb1[2], xb2[2], xb3[2];
        xb0[0] = xp[0]; xb0[1] = xp[1];
        xb1[0] = xp[2]; xb1[1] = xp[3];
        xb2[0] = xp[4]; xb2[1] = xp[5];
        xb3[0] = xp[6]; xb3[1] = xp[7];

#define L0STEP(XB, S, TN)                                                    \
        {                                                                    \
            v2h xh0 = pkh(XB[0].x, XB[0].y), xh1 = pkh(XB[0].z, XB[0].w);    \
            v2h xh2 = pkh(XB[1].x, XB[1].y), xh3 = pkh(XB[1].z, XB[1].w);    \
            { int tn = (TN) > 511 ? 511 : (TN);                              \
              XB[0] = xp[2*tn]; XB[1] = xp[2*tn + 1]; }                      \
            float a0 = bb[0], a1 = bb[1], a2 = bb[2], a3 = bb[3];            \
            DOT2(a0, wx[0][0], xh0); DOT2(a1, wx[1][0], xh0);                \
            DOT2(a2, wx[2][0], xh0); DOT2(a3, wx[3][0], xh0);                \
            DOT2(a0, wx[0][1], xh1); DOT2(a1, wx[1][1], xh1);                \
            DOT2(a2, wx[2][1], xh1); DOT2(a3, wx[3][1], xh1);                \
            DOT2(a0, wx[0][2], xh2); DOT2(a1, wx[1][2], xh2);                \
            DOT2(a2, wx[2][2], xh2); DOT2(a3, wx[3][2], xh2);                \
            DOT2(a0, wx[0][3], xh3); DOT2(a1, wx[1][3], xh3);                \
            DOT2(a2, wx[2][3], xh3); DOT2(a3, wx[3][3], xh3);                \
            _Pragma("unroll")                                                \
            for (int k = 0; k < 5; ++k) {                                    \
                DOT2(a0, wA[0][k], hv[k]); DOT2(a1, wA[1][k], hv[k]);        \
                DOT2(a2, wA[2][k], hv[k]); DOT2(a3, wA[3][k], hv[k]);        \
            }                                                                \
            float i_ = SIGM(a0), f_ = SIGM(a1);                              \
            float g_ = TANHP(a2), o_ = SIGM(a3);                             \
            cc = fmaf(f_, cc, i_ * g_);                                      \
            float tc_ = (2.0f * L2E) * cc;                                   \
            hj = o_ * TANHP(tc_);                                            \
            wbase[(S)*128 + l16] = (__fp16)hj;                               \
            { const v2h* rb_ = (const v2h*)(wbase + (S)*128);                \
              hv[0] = rb_[0]; hv[1] = rb_[1]; hv[2] = rb_[2];                \
              hv[3] = rb_[3]; hv[4] = rb_[4]; }                              \
        }

        for (int it = 0; it < 64; ++it) {
            const int tb = 8 * it;
            L0STEP(xb0, 0, tb + 4)
            L0STEP(xb1, 1, tb + 5)
            L0STEP(xb2, 2, tb + 6)
            L0STEP(xb3, 3, tb + 7)
            __syncthreads();
            L0STEP(xb0, 4, tb + 8)
            L0STEP(xb1, 5, tb + 9)
            L0STEP(xb2, 6, tb + 10)
            L0STEP(xb3, 7, tb + 11)
            __syncthreads();
        }
#undef L0STEP

        if (act) {
            out[4096          + e * 10 + l16] = hj;   // h0_T
            out[4096 + 81920  + e * 10 + l16] = cc;   // c0_T
        }

    } else {
        // ================= LAYER-1 (consumer) waves =================
        v2h wA[4][5], wB[4][5];  float bb[4];
        #pragma unroll
        for (int g = 0; g < 4; ++g) {
            const int r = g * 10 + j;
            const float sc = (g == 2) ? 2.0f * L2E : L2E;
            #pragma unroll
            for (int k = 0; k < 5; ++k) wA[g][k] = pkh(Whh1[r*10 + 2*k] * sc, Whh1[r*10 + 2*k+1] * sc);
            #pragma unroll
            for (int k = 0; k < 5; ++k) wB[g][k] = pkh(Wih1[r*10 + 2*k] * sc, Wih1[r*10 + 2*k+1] * sc);
            bb[g] = (bih1[r] + bhh1[r]) * sc;
        }
        const float wfc = act ? Wfc[j] : 0.0f;
        v2h hv[5];
        #pragma unroll
        for (int k = 0; k < 5; ++k) hv[k] = pkh(hid[40960 + e*10 + 2*k], hid[40960 + e*10 + 2*k+1]);
        float cc = cel[40960 + e * 10 + j];
        float hj = 0.0f;

        __fp16* const h1w = &h1buf[eIB][0];
        const __fp16* const rbase = &h0buf[0][eIB][0];   // slot stride 128 halves

#define L1STEP(S)                                                            \
        {                                                                    \
            const v2h* ir_ = (const v2h*)(rbase + (S)*128);                  \
            v2h i0_ = ir_[0], i1_ = ir_[1], i2_ = ir_[2],                    \
                i3_ = ir_[3], i4_ = ir_[4];                                  \
            float a0 = bb[0], a1 = bb[1], a2 = bb[2], a3 = bb[3];            \
            _Pragma("unroll")                                                \
            for (int k = 0; k < 5; ++k) {                                    \
                DOT2(a0, wA[0][k], hv[k]); DOT2(a1, wA[1][k], hv[k]);        \
                DOT2(a2, wA[2][k], hv[k]); DOT2(a3, wA[3][k], hv[k]);        \
            }                                                                \
            DOT2(a0, wB[0][0], i0_); DOT2(a1, wB[1][0], i0_);                \
            DOT2(a2, wB[2][0], i0_); DOT2(a3, wB[3][0], i0_);                \
            DOT2(a0, wB[0][1], i1_); DOT2(a1, wB[1][1], i1_);                \
            DOT2(a2, wB[2][1], i1_); DOT2(a3, wB[3][1], i1_);                \
            DOT2(a0, wB[0][2], i2_); DOT2(a1, wB[1][2], i2_);                \
            DOT2(a2, wB[2][2], i2_); DOT2(a3, wB[3][2], i2_);                \
            DOT2(a0, wB[0][3], i3_); DOT2(a1, wB[1][3], i3_);                \
            DOT2(a2, wB[2][3], i3_); DOT2(a3, wB[3][3], i3_);                \
            DOT2(a0, wB[0][4], i4_); DOT2(a1, wB[1][4], i4_);                \
            DOT2(a2, wB[2][4], i4_); DOT2(a3, wB[3][4], i4_);                \
            float i_ = SIGM(a0), f_ = SIGM(a1);                              \
            float g_ = TANHP(a2), o_ = SIGM(a3);                             \
            cc = fmaf(f_, cc, i_ * g_);                                      \
            float tc_ = (2.0f * L2E) * cc;                                   \
            hj = o_ * TANHP(tc_);                                            \
            h1w[l16] = (__fp16)hj;                                           \
            { const v2h* rb_ = (const v2h*)h1w;                              \
              hv[0] = rb_[0]; hv[1] = rb_[1]; hv[2] = rb_[2];                \
              hv[3] = rb_[3]; hv[4] = rb_[4]; }                              \
        }

        for (int it = 0; it < 64; ++it) {
            __syncthreads();
            L1STEP(0)
            L1STEP(1)
            L1STEP(2)
            L1STEP(3)
            __syncthreads();
            L1STEP(4)
            L1STEP(5)
            L1STEP(6)
            L1STEP(7)
        }
#undef L1STEP

        float p = hj * wfc;
        #pragma unroll
        for (int off = 8; off > 0; off >>= 1) p += __shfl_xor(p, off, 16);
        if (l16 == 0) out[e] = p + bfc[0];
        if (act) {
            out[4096 + 40960  + e * 10 + l16] = hj;   // h1_T
            out[4096 + 122880 + e * 10 + l16] = cc;   // c1_T
        }
    }
}

extern "C" void kernel_launch(void* const* d_in, const int* in_sizes, int n_in,
                              void* d_out, int out_size, void* d_ws, size_t ws_size,
                              hipStream_t stream) {
    const float* x    = (const float*)d_in[0];
    const float* hid  = (const float*)d_in[1];
    const float* cel  = (const float*)d_in[2];
    const float* Wih0 = (const float*)d_in[3];
    const float* Whh0 = (const float*)d_in[4];
    const float* bih0 = (const float*)d_in[5];
    const float* bhh0 = (const float*)d_in[6];
    const float* Wih1 = (const float*)d_in[7];
    const float* Whh1 = (const float*)d_in[8];
    const float* bih1 = (const float*)d_in[9];
    const float* bhh1 = (const float*)d_in[10];
    const float* Wfc  = (const float*)d_in[11];
    const float* bfc  = (const float*)d_in[12];

    hipLaunchKernelGGL(lstm2_r6, dim3(512), dim3(256), 0, stream,
                       x, hid, cel, Wih0, Whh0, bih0, bhh0,
                       Wih1, Whh1, bih1, bhh1, Wfc, bfc,
                       (float*)d_out);
}